// Round 12
// baseline (1044.321 us; speedup 1.0000x reference)
//
#include <hip/hip_runtime.h>
#include <hip/hip_bf16.h>

typedef __hip_bfloat16 bf16;
typedef __attribute__((ext_vector_type(8))) short bf16x8;
typedef __attribute__((ext_vector_type(4))) short bf16x4;
typedef __attribute__((ext_vector_type(4))) float f32x4;

#define T_STEPS 128
#define NWG 128
#define NFLAGS 512   // one flag per wave (128 WG x 4 waves)
#define ZSLOTS 8
// B=64, I=256, H=512, E=4, G=2048. 128 WGs x 256 thr (verified R10/R11 base).
// R12 delta vs R11: poll backoff = dependent-FMA spin (keeps SIMDs busy ->
// no DVFS downclock; halves poll LLC traffic) instead of s_sleep(2).
// Everything else verbatim R11.

__device__ inline unsigned short f2bf(float f) {
    bf16 b = __float2bfloat16(f);
    return *reinterpret_cast<unsigned short*>(&b);
}

// ---------------- prep kernels ----------------

// W2T[o][e*512+hh] = Wh[e][o][hh]   (bf16, [2048][2048])
__global__ void prep_w2t(const float* __restrict__ Wh, bf16* __restrict__ W2T) {
    int idx = blockIdx.x * 256 + threadIdx.x;          // 2048*2048
    int o = idx >> 11, k = idx & 2047;
    int e = k >> 9, hh = k & 511;
    W2T[idx] = __float2bfloat16(Wh[((size_t)((e << 11) + o) << 9) + hh]);
}

// W1T[o][e*256+i] = Wi[e][o][i]     (bf16, [2048][1024])
__global__ void prep_w1t(const float* __restrict__ Wi, bf16* __restrict__ W1T) {
    int idx = blockIdx.x * 256 + threadIdx.x;          // 2048*1024
    int o = idx >> 10, k = idx & 1023;
    int e = k >> 8, i = k & 255;
    W1T[idx] = __float2bfloat16(Wi[((size_t)((e << 11) + o) << 8) + i]);
}

// A1[t*64+b][e*256+i] = coef[b][e] * x[t][b][i]   (bf16, [8192][1024])
__global__ void prep_a1(const float* __restrict__ x, const float* __restrict__ coef,
                        bf16* __restrict__ A1) {
    int idx = blockIdx.x * 256 + threadIdx.x;          // 8192*1024
    int row = idx >> 10, k = idx & 1023;
    int b = row & 63;
    int e = k >> 8, i = k & 255;
    A1[idx] = __float2bfloat16(coef[(b << 2) + e] * x[((size_t)row << 8) + i]);
}

// biasmix[b][o] = sum_e coef[b][e]*(bi[e][o]+bh[e][o])   (f32, [64][2048])
__global__ void prep_bias(const float* __restrict__ coef, const float* __restrict__ bi,
                          const float* __restrict__ bh, float* __restrict__ biasmix) {
    int idx = blockIdx.x * 256 + threadIdx.x;          // 64*2048
    int b = idx >> 11, o = idx & 2047;
    float s = 0.f;
#pragma unroll
    for (int e = 0; e < 4; ++e)
        s += coef[(b << 2) + e] * (bi[(e << 11) + o] + bh[(e << 11) + o]);
    biasmix[idx] = s;
}

// h0 -> slot 0 in TRANSPOSED layout hq[ug][samp][uu]; zero the 512 flags
__global__ void prep_h0(const float* __restrict__ h0, bf16* __restrict__ hbuf,
                        unsigned* __restrict__ flags) {
    int idx = blockIdx.x * 256 + threadIdx.x;          // 32768
    if (idx < NFLAGS) flags[idx] = 0u;
    int ug = idx >> 8, rem = idx & 255;
    int samp = rem >> 2, uu = rem & 3;
    hbuf[idx] = __float2bfloat16(h0[((size_t)samp << 9) + (ug << 2) + uu]);
}

// ---------------- main recurrent kernel ----------------
__launch_bounds__(256, 1)
__global__ void lstm_rec(const bf16* __restrict__ W2T, const bf16* __restrict__ W1T,
                         const bf16* __restrict__ A1, const float* __restrict__ biasmix,
                         bf16* h_buf, const float* __restrict__ coef,
                         const float* __restrict__ c0, float* __restrict__ out,
                         unsigned* __restrict__ flags) {
    __shared__ bf16x8 W2L[4 * 16 * 64];   // [e][kk][lane] fragments, 64KB
    __shared__ bf16x8 W1L[32 * 64];       // [kk][lane] fragments, 32KB

    const int wg  = blockIdx.x;       // 0..127
    const int j0  = wg << 2;
    const int tid = threadIdx.x;
    const int lane = tid & 63;
    const int wv  = tid >> 6;         // wave 0..3 -> samples 16*wv..+15

    const int rlo  = lane & 15;       // MFMA col within 16: rlo = q*4 + jj
    const int kg   = lane >> 4;       // k-group / C row-quad
    const int arow = (wv << 4) + rlo; // A-row (sample) this lane loads
    const int q    = rlo >> 2;        // gate index of this lane's col
    const int jj   = rlo & 3;         // unit-within-WG
    const int samp = (wv << 4) + (kg << 2) + q;   // cell this lane owns
    const int o_ln = (q << 9) + j0 + jj;          // this lane's gate column

    // ---- build LDS weight fragments (verbatim R6/R10/R11) ----
    for (int g = tid; g < 4096; g += 256) {
        int e = g >> 10, kk = (g >> 6) & 15, l = g & 63;
        int rl = l & 15, kgg = l >> 4;
        int o = ((rl >> 2) << 9) + j0 + (rl & 3);
        W2L[g] = *(const bf16x8*)(W2T + ((size_t)o << 11) + (e << 9) + (kk << 5) + (kgg << 3));
    }
    for (int g = tid; g < 2048; g += 256) {
        int kk = g >> 6, l = g & 63;
        int rl = l & 15, kgg = l >> 4;
        int o = ((rl >> 2) << 9) + j0 + (rl & 3);
        W1L[g] = *(const bf16x8*)(W1T + ((size_t)o << 10) + (kk << 5) + (kgg << 3));
    }

    // ---- per-lane constants in registers ----
    float bias_r[4];
    float4 cw[4];
#pragma unroll
    for (int r = 0; r < 4; ++r) {
        int row = (wv << 4) + (kg << 2) + r;
        bias_r[r] = biasmix[((size_t)row << 11) + o_ln];
        cw[r] = *(const float4*)(coef + (row << 2));
    }
    float c_reg = c0[((size_t)samp << 9) + j0 + jj];

    __syncthreads();

    f32x4 acc0, acc1, acc2, acc3;   // input-part accumulators (overlap slot)
    {
        const bf16x8* xa = (const bf16x8*)A1 + ((size_t)arow << 7) + kg;
        acc0 = (f32x4){0.f, 0.f, 0.f, 0.f}; acc1 = acc0; acc2 = acc0; acc3 = acc0;
#pragma unroll
        for (int kk = 0; kk < 32; ++kk) {
            bf16x8 a = xa[kk << 2];
            bf16x8 b = W1L[(kk << 6) + lane];
            f32x4& ac = (kk & 3) == 0 ? acc0 : (kk & 3) == 1 ? acc1 : (kk & 3) == 2 ? acc2 : acc3;
            ac = __builtin_amdgcn_mfma_f32_16x16x32_bf16(a, b, ac, 0, 0, 0);
        }
    }

    float spin = 1.0f;   // FMA-backoff accumulator (kept live via asm sink)

    for (int t = 0; t < T_STEPS; ++t) {
        // ---- wait for epoch t: per-wave poll; FMA-spin backoff (no s_sleep,
        //      keeps SIMDs busy so the power governor holds clocks up) ----
        if (t) {
            const unsigned long long* f64 = (const unsigned long long*)flags + (lane << 2);
            const unsigned tt = (unsigned)t;
            while (true) {
                unsigned long long v0 = __hip_atomic_load(f64 + 0, __ATOMIC_RELAXED, __HIP_MEMORY_SCOPE_AGENT);
                unsigned long long v1 = __hip_atomic_load(f64 + 1, __ATOMIC_RELAXED, __HIP_MEMORY_SCOPE_AGENT);
                unsigned long long v2 = __hip_atomic_load(f64 + 2, __ATOMIC_RELAXED, __HIP_MEMORY_SCOPE_AGENT);
                unsigned long long v3 = __hip_atomic_load(f64 + 3, __ATOMIC_RELAXED, __HIP_MEMORY_SCOPE_AGENT);
                if ((unsigned)v0 >= tt && (unsigned)(v0 >> 32) >= tt &&
                    (unsigned)v1 >= tt && (unsigned)(v1 >> 32) >= tt &&
                    (unsigned)v2 >= tt && (unsigned)(v2 >> 32) >= tt &&
                    (unsigned)v3 >= tt && (unsigned)(v3 >> 32) >= tt) break;
#pragma unroll
                for (int i = 0; i < 64; ++i)           // ~256cy dependent chain
                    spin = __builtin_fmaf(spin, 1.0000001f, 1e-30f);
                asm volatile("" :: "v"(spin));          // keep live (no DCE)
            }
            if ((t & (ZSLOTS - 1)) == 0) {   // slow path: rendezvous + L2 inv (no wbl2)
                __syncthreads();
                if (tid < 64) __builtin_amdgcn_fence(__ATOMIC_ACQUIRE, "agent");
                __syncthreads();
            }
        }

        // h slots in TRANSPOSED layout: hq[ug][samp], 8B entries, 64KB/slot
        const bf16* hin  = h_buf + ((size_t)(t & (ZSLOTS - 1)) << 15);
        bf16*       hout = h_buf + ((size_t)((t + 1) & (ZSLOTS - 1)) << 15);

        // ---- hidden GEMM: preload 16 A-frags (two 8B loads each), 4 experts ----
        f32x4 e0 = {0.f, 0.f, 0.f, 0.f}, e1 = e0, e2 = e0, e3 = e0;
        {
            const bf16x4* hb = (const bf16x4*)hin;
            bf16x8 areg[16];
#pragma unroll
            for (int kk = 0; kk < 16; ++kk) {
                int ug = (kk << 3) + (kg << 1);
                bf16x4 lo = hb[(ug << 6) + arow];
                bf16x4 hi = hb[((ug + 1) << 6) + arow];
                areg[kk] = __builtin_shufflevector(lo, hi, 0, 1, 2, 3, 4, 5, 6, 7);
            }
#pragma unroll
            for (int kk = 0; kk < 16; ++kk) {
                e0 = __builtin_amdgcn_mfma_f32_16x16x32_bf16(areg[kk], W2L[(kk << 6) + lane       ], e0, 0, 0, 0);
                e1 = __builtin_amdgcn_mfma_f32_16x16x32_bf16(areg[kk], W2L[(kk << 6) + lane + 1024], e1, 0, 0, 0);
                e2 = __builtin_amdgcn_mfma_f32_16x16x32_bf16(areg[kk], W2L[(kk << 6) + lane + 2048], e2, 0, 0, 0);
                e3 = __builtin_amdgcn_mfma_f32_16x16x32_bf16(areg[kk], W2L[(kk << 6) + lane + 3072], e3, 0, 0, 0);
            }
        }

        // ---- epilogue in registers: g = sum_e coef*acc_e + xg + bias ----
        f32x4 gv;
        {
            f32x4 xin = (acc0 + acc1) + (acc2 + acc3);
#pragma unroll
            for (int r = 0; r < 4; ++r)
                gv[r] = e0[r] * cw[r].x + e1[r] * cw[r].y + e2[r] * cw[r].z + e3[r] * cw[r].w
                      + xin[r] + bias_r[r];
        }

        // ---- gate exchange among 4 gate-lanes (xor 4/8/12) — verified R10 ----
        const bool b0 = (q & 1), b1 = (q & 2);
        float own = b1 ? (b0 ? gv[3] : gv[2]) : (b0 ? gv[1] : gv[0]);   // g[q]
        float s1  = b1 ? (b0 ? gv[2] : gv[3]) : (b0 ? gv[0] : gv[1]);   // g[q^1]
        float s2  = b1 ? (b0 ? gv[1] : gv[0]) : (b0 ? gv[3] : gv[2]);   // g[q^2]
        float s3  = b1 ? (b0 ? gv[0] : gv[1]) : (b0 ? gv[2] : gv[3]);   // g[q^3]
        float r1 = __shfl_xor(s1, 4);
        float r2 = __shfl_xor(s2, 8);
        float r3 = __shfl_xor(s3, 12);
        float iG = (q == 0) ? own : (q == 1) ? r1 : (q == 2) ? r2 : r3;
        float fG = (q == 0) ? r1 : (q == 1) ? own : (q == 2) ? r3 : r2;
        float cG = (q == 0) ? r2 : (q == 1) ? r3 : (q == 2) ? own : r1;
        float oG = (q == 0) ? r3 : (q == 1) ? r2 : (q == 2) ? r1 : own;

        // ---- cell update (1 cell per lane) ----
        float ig = 1.f / (1.f + __expf(-iG));
        float fg = 1.f / (1.f + __expf(-fG));
        float cc = tanhf(cG);
        float og = 1.f / (1.f + __expf(-oG));
        float cn = fg * c_reg + ig * cc;
        float hv = og * tanhf(cn);
        c_reg = cn;

        // ---- pack 4 units of my sample via butterfly over jj (verified R10) ----
        unsigned u = (unsigned)f2bf(hv);
        unsigned w = (unsigned)__shfl_xor((int)u, 1);
        unsigned pair = (jj & 1) ? (w | (u << 16)) : (u | (w << 16));
        unsigned p2 = (unsigned)__shfl_xor((int)pair, 2);
        unsigned long long v64 = (jj & 2)
            ? ((unsigned long long)p2 | ((unsigned long long)pair << 32))
            : ((unsigned long long)pair | ((unsigned long long)p2 << 32));
        // TRANSPOSED store: wave's 16 stores = one contiguous 128B line
        if (jj == 0)
            __hip_atomic_store((unsigned long long*)hout + (wg << 6) + samp,
                               v64, __ATOMIC_RELAXED, __HIP_MEMORY_SCOPE_AGENT);

        // ---- release: per-wave drain (1 line) + per-wave flag ----
        asm volatile("s_waitcnt vmcnt(0)" ::: "memory");
        if (lane == 0)
            __hip_atomic_store(&flags[(wg << 2) + wv], (unsigned)(t + 1),
                               __ATOMIC_RELAXED, __HIP_MEMORY_SCOPE_AGENT);

        // ---- post-arrive (off critical path): out stores + next input GEMM ----
        out[((size_t)t << 15) + ((size_t)samp << 9) + j0 + jj] = hv;
        if (t == T_STEPS - 1) {
            size_t base = (size_t)T_STEPS << 15;
            out[base + ((size_t)samp << 9) + j0 + jj] = hv;
            out[base + (1 << 15) + ((size_t)samp << 9) + j0 + jj] = cn;
        }
        if (t + 1 < T_STEPS) {
            const bf16x8* xa = (const bf16x8*)A1 + ((size_t)(((t + 1) << 6) + arow) << 7) + kg;
            acc0 = (f32x4){0.f, 0.f, 0.f, 0.f}; acc1 = acc0; acc2 = acc0; acc3 = acc0;
#pragma unroll
            for (int kk = 0; kk < 32; ++kk) {
                bf16x8 a = xa[kk << 2];
                bf16x8 b = W1L[(kk << 6) + lane];
                f32x4& ac = (kk & 3) == 0 ? acc0 : (kk & 3) == 1 ? acc1 : (kk & 3) == 2 ? acc2 : acc3;
                ac = __builtin_amdgcn_mfma_f32_16x16x32_bf16(a, b, ac, 0, 0, 0);
            }
        }
    }
}

// ---------------- launch (ws layout verbatim R11) ----------------
extern "C" void kernel_launch(void* const* d_in, const int* in_sizes, int n_in,
                              void* d_out, int out_size, void* d_ws, size_t ws_size,
                              hipStream_t stream) {
    const float* x    = (const float*)d_in[0];
    const float* h0   = (const float*)d_in[1];
    const float* c0   = (const float*)d_in[2];
    const float* coef = (const float*)d_in[3];
    const float* Wi   = (const float*)d_in[4];
    const float* bi   = (const float*)d_in[5];
    const float* Wh   = (const float*)d_in[6];
    const float* bh   = (const float*)d_in[7];
    float* out = (float*)d_out;

    char* ws = (char*)d_ws;
    bf16*   W2T     = (bf16*)(ws);                                   // 8 MB
    bf16*   W1T     = (bf16*)(ws + (8u  << 20));                     // 4 MB
    bf16*   A1      = (bf16*)(ws + (12u << 20));                     // 16 MB
    float*  biasmix = (float*)(ws + (28u << 20));                    // 512 KB
    bf16*   h_buf   = (bf16*)(ws + (28u << 20) + (512u << 10));      // 512 KB (8x64KB)
    unsigned* flags = (unsigned*)(ws + (29u << 20));                 // 2 KB

    prep_w2t <<<16384, 256, 0, stream>>>(Wh, W2T);
    prep_w1t <<< 8192, 256, 0, stream>>>(Wi, W1T);
    prep_a1  <<<32768, 256, 0, stream>>>(x, coef, A1);
    prep_bias<<<  512, 256, 0, stream>>>(coef, bi, bh, biasmix);
    prep_h0  <<<  128, 256, 0, stream>>>(h0, h_buf, flags);

    void* args[] = {(void*)&W2T, (void*)&W1T, (void*)&A1, (void*)&biasmix,
                    (void*)&h_buf, (void*)&coef, (void*)&c0, (void*)&out, (void*)&flags};
    hipLaunchCooperativeKernel((void*)lstm_rec, dim3(NWG), dim3(256), args, 0, stream);
}

// Round 13
// 926.161 us; speedup vs baseline: 1.1276x; 1.1276x over previous
//
#include <hip/hip_runtime.h>
#include <hip/hip_bf16.h>

typedef __hip_bfloat16 bf16;
typedef __attribute__((ext_vector_type(8))) short bf16x8;
typedef __attribute__((ext_vector_type(4))) short bf16x4;
typedef __attribute__((ext_vector_type(4))) float f32x4;

#define T_STEPS 128
#define NWG 256        // 2 halves x 128 WGs, 128 threads (2 waves) each
#define HWGS 128       // WGs per half
#define NFLAGS 512     // 2 halves x 256 per-wave flags
#define ZSLOTS 8
// B=64, I=256, H=512, E=4, G=2048. R13: batch split into 2 INDEPENDENT halves
// (samples 0..31 / 32..63) -- the recurrence never mixes samples, so the two
// halves never sync with each other. Each half: 128 WGs (1/CU, full chip now),
// WG = 2 waves, owns 4 hidden units j0=4*wgh (16 gate cols), M=32 samples.
// Per-wave tile 16 samples x 16 cols, hidden K=512 x 4 experts (64 MFMA) --
// arithmetic verbatim R12, only the M dimension narrowed and wave count 4->2.
// h exchange per half: transposed hq[ug=wgh][samp32] 8B entries, 32KB/slot,
// 8-slot rotation. Sync skeleton verbatim R12 (sc1 stores + vmcnt + per-wave
// flags + FMA-spin poll + acquire-inv rendezvous every ZSLOTS steps).

__device__ inline unsigned short f2bf(float f) {
    bf16 b = __float2bfloat16(f);
    return *reinterpret_cast<unsigned short*>(&b);
}

// ---------------- prep kernels ----------------

// W2T[o][e*512+hh] = Wh[e][o][hh]   (bf16, [2048][2048])
__global__ void prep_w2t(const float* __restrict__ Wh, bf16* __restrict__ W2T) {
    int idx = blockIdx.x * 256 + threadIdx.x;          // 2048*2048
    int o = idx >> 11, k = idx & 2047;
    int e = k >> 9, hh = k & 511;
    W2T[idx] = __float2bfloat16(Wh[((size_t)((e << 11) + o) << 9) + hh]);
}

// W1T[o][e*256+i] = Wi[e][o][i]     (bf16, [2048][1024])
__global__ void prep_w1t(const float* __restrict__ Wi, bf16* __restrict__ W1T) {
    int idx = blockIdx.x * 256 + threadIdx.x;          // 2048*1024
    int o = idx >> 10, k = idx & 1023;
    int e = k >> 8, i = k & 255;
    W1T[idx] = __float2bfloat16(Wi[((size_t)((e << 11) + o) << 8) + i]);
}

// A1[t*64+b][e*256+i] = coef[b][e] * x[t][b][i]   (bf16, [8192][1024])
__global__ void prep_a1(const float* __restrict__ x, const float* __restrict__ coef,
                        bf16* __restrict__ A1) {
    int idx = blockIdx.x * 256 + threadIdx.x;          // 8192*1024
    int row = idx >> 10, k = idx & 1023;
    int b = row & 63;
    int e = k >> 8, i = k & 255;
    A1[idx] = __float2bfloat16(coef[(b << 2) + e] * x[((size_t)row << 8) + i]);
}

// biasmix[b][o] = sum_e coef[b][e]*(bi[e][o]+bh[e][o])   (f32, [64][2048])
__global__ void prep_bias(const float* __restrict__ coef, const float* __restrict__ bi,
                          const float* __restrict__ bh, float* __restrict__ biasmix) {
    int idx = blockIdx.x * 256 + threadIdx.x;          // 64*2048
    int b = idx >> 11, o = idx & 2047;
    float s = 0.f;
#pragma unroll
    for (int e = 0; e < 4; ++e)
        s += coef[(b << 2) + e] * (bi[(e << 11) + o] + bh[(e << 11) + o]);
    biasmix[idx] = s;
}

// h0 -> slot 0 per half, transposed hq[ug][samp32][uu]; zero the 512 flags
__global__ void prep_h0(const float* __restrict__ h0, bf16* __restrict__ hbuf,
                        unsigned* __restrict__ flags) {
    int idx = blockIdx.x * 256 + threadIdx.x;          // 64*512 = 32768
    if (idx < NFLAGS) flags[idx] = 0u;
    int s = idx >> 9, u = idx & 511;
    int half = s >> 5, s32 = s & 31;
    int ug = u >> 2, uu = u & 3;
    // half base = half * ZSLOTS * 16384 elems; slot 0
    hbuf[(size_t)half * (ZSLOTS * 16384) + ((ug << 5) + s32) * 4 + uu] =
        __float2bfloat16(h0[((size_t)s << 9) + u]);
}

// ---------------- main recurrent kernel ----------------
__launch_bounds__(128, 1)
__global__ void lstm_rec(const bf16* __restrict__ W2T, const bf16* __restrict__ W1T,
                         const bf16* __restrict__ A1, const float* __restrict__ biasmix,
                         bf16* h_buf, const float* __restrict__ coef,
                         const float* __restrict__ c0, float* __restrict__ out,
                         unsigned* __restrict__ flags) {
    __shared__ bf16x8 W2L[4 * 16 * 64];   // [e][kk][lane] fragments, 64KB
    __shared__ bf16x8 W1L[32 * 64];       // [kk][lane] fragments, 32KB

    const int wg   = blockIdx.x;      // 0..255
    const int half = wg >> 7;         // 0,1: samples half*32 .. +31
    const int wgh  = wg & 127;        // WG within half; owns units j0..j0+3
    const int j0   = wgh << 2;
    const int tid  = threadIdx.x;     // 0..127
    const int lane = tid & 63;
    const int wv   = tid >> 6;        // wave 0,1 -> local sample rows 16*wv..+15

    const int rlo  = lane & 15;       // MFMA col within 16: rlo = q*4 + jj
    const int kg   = lane >> 4;       // k-group / C row-quad
    const int q    = rlo >> 2;        // gate index of this lane's col
    const int jj   = rlo & 3;         // unit-within-WG
    const int s32  = (wv << 4) + (kg << 2) + q;     // local sample of my cell
    const int samp = (half << 5) + s32;             // global sample
    const int arow = (half << 5) + (wv << 4) + rlo; // global A-row this lane loads
    const int a32  = (wv << 4) + rlo;               // local A-row (h buffer)
    const int o_ln = (q << 9) + j0 + jj;            // this lane's gate column

    // ---- build LDS weight fragments (layout verbatim R12; stride 128) ----
    for (int g = tid; g < 4096; g += 128) {
        int e = g >> 10, kk = (g >> 6) & 15, l = g & 63;
        int rl = l & 15, kgg = l >> 4;
        int o = ((rl >> 2) << 9) + j0 + (rl & 3);
        W2L[g] = *(const bf16x8*)(W2T + ((size_t)o << 11) + (e << 9) + (kk << 5) + (kgg << 3));
    }
    for (int g = tid; g < 2048; g += 128) {
        int kk = g >> 6, l = g & 63;
        int rl = l & 15, kgg = l >> 4;
        int o = ((rl >> 2) << 9) + j0 + (rl & 3);
        W1L[g] = *(const bf16x8*)(W1T + ((size_t)o << 10) + (kk << 5) + (kgg << 3));
    }

    // ---- per-lane constants in registers ----
    float bias_r[4];
    float4 cw[4];
#pragma unroll
    for (int r = 0; r < 4; ++r) {
        int row = (half << 5) + (wv << 4) + (kg << 2) + r;   // global sample row
        bias_r[r] = biasmix[((size_t)row << 11) + o_ln];
        cw[r] = *(const float4*)(coef + (row << 2));
    }
    float c_reg = c0[((size_t)samp << 9) + j0 + jj];

    // per-half h buffer (8 slots x 16384 elems) and flag block
    bf16* hB = h_buf + (size_t)half * (ZSLOTS * 16384);
    unsigned* flagB = flags + (half << 8);

    __syncthreads();

    f32x4 acc0, acc1, acc2, acc3;   // input-part accumulators (overlap slot)
    {
        const bf16x8* xa = (const bf16x8*)A1 + ((size_t)arow << 7) + kg;
        acc0 = (f32x4){0.f, 0.f, 0.f, 0.f}; acc1 = acc0; acc2 = acc0; acc3 = acc0;
#pragma unroll
        for (int kk = 0; kk < 32; ++kk) {
            bf16x8 a = xa[kk << 2];
            bf16x8 b = W1L[(kk << 6) + lane];
            f32x4& ac = (kk & 3) == 0 ? acc0 : (kk & 3) == 1 ? acc1 : (kk & 3) == 2 ? acc2 : acc3;
            ac = __builtin_amdgcn_mfma_f32_16x16x32_bf16(a, b, ac, 0, 0, 0);
        }
    }

    float spin = 1.0f;   // FMA-backoff accumulator (kept live via asm sink)

    for (int t = 0; t < T_STEPS; ++t) {
        // ---- wait for epoch t: poll own half's 256 wave-flags (2 u64/lane) ----
        if (t) {
            const unsigned long long* f64 = (const unsigned long long*)flagB + (lane << 1);
            const unsigned tt = (unsigned)t;
            while (true) {
                unsigned long long v0 = __hip_atomic_load(f64 + 0, __ATOMIC_RELAXED, __HIP_MEMORY_SCOPE_AGENT);
                unsigned long long v1 = __hip_atomic_load(f64 + 1, __ATOMIC_RELAXED, __HIP_MEMORY_SCOPE_AGENT);
                if ((unsigned)v0 >= tt && (unsigned)(v0 >> 32) >= tt &&
                    (unsigned)v1 >= tt && (unsigned)(v1 >> 32) >= tt) break;
#pragma unroll
                for (int i = 0; i < 64; ++i)           // ~256cy dependent chain
                    spin = __builtin_fmaf(spin, 1.0000001f, 1e-30f);
                asm volatile("" :: "v"(spin));          // keep live (no DCE)
            }
            if ((t & (ZSLOTS - 1)) == 0) {   // slow path: rendezvous + L2 inv (no wbl2)
                __syncthreads();
                if (tid < 64) __builtin_amdgcn_fence(__ATOMIC_ACQUIRE, "agent");
                __syncthreads();
            }
        }

        // h slots transposed: hq[ug=wgh][samp32], 8B entries, 32KB/slot
        const bf16* hin  = hB + (((size_t)t & (ZSLOTS - 1)) << 14);
        bf16*       hout = hB + (((size_t)(t + 1) & (ZSLOTS - 1)) << 14);

        // ---- hidden GEMM: preload 16 A-frags (two 8B loads each), 4 experts ----
        f32x4 e0 = {0.f, 0.f, 0.f, 0.f}, e1 = e0, e2 = e0, e3 = e0;
        {
            const bf16x4* hb = (const bf16x4*)hin;
            bf16x8 areg[16];
#pragma unroll
            for (int kk = 0; kk < 16; ++kk) {
                int ug = (kk << 3) + (kg << 1);
                bf16x4 lo = hb[(ug << 5) + a32];
                bf16x4 hi = hb[((ug + 1) << 5) + a32];
                areg[kk] = __builtin_shufflevector(lo, hi, 0, 1, 2, 3, 4, 5, 6, 7);
            }
#pragma unroll
            for (int kk = 0; kk < 16; ++kk) {
                e0 = __builtin_amdgcn_mfma_f32_16x16x32_bf16(areg[kk], W2L[(kk << 6) + lane       ], e0, 0, 0, 0);
                e1 = __builtin_amdgcn_mfma_f32_16x16x32_bf16(areg[kk], W2L[(kk << 6) + lane + 1024], e1, 0, 0, 0);
                e2 = __builtin_amdgcn_mfma_f32_16x16x32_bf16(areg[kk], W2L[(kk << 6) + lane + 2048], e2, 0, 0, 0);
                e3 = __builtin_amdgcn_mfma_f32_16x16x32_bf16(areg[kk], W2L[(kk << 6) + lane + 3072], e3, 0, 0, 0);
            }
        }

        // ---- epilogue in registers: g = sum_e coef*acc_e + xg + bias ----
        f32x4 gv;
        {
            f32x4 xin = (acc0 + acc1) + (acc2 + acc3);
#pragma unroll
            for (int r = 0; r < 4; ++r)
                gv[r] = e0[r] * cw[r].x + e1[r] * cw[r].y + e2[r] * cw[r].z + e3[r] * cw[r].w
                      + xin[r] + bias_r[r];
        }

        // ---- gate exchange among 4 gate-lanes (xor 4/8/12) — verified R10 ----
        const bool b0 = (q & 1), b1 = (q & 2);
        float own = b1 ? (b0 ? gv[3] : gv[2]) : (b0 ? gv[1] : gv[0]);   // g[q]
        float s1  = b1 ? (b0 ? gv[2] : gv[3]) : (b0 ? gv[0] : gv[1]);   // g[q^1]
        float s2  = b1 ? (b0 ? gv[1] : gv[0]) : (b0 ? gv[3] : gv[2]);   // g[q^2]
        float s3  = b1 ? (b0 ? gv[0] : gv[1]) : (b0 ? gv[2] : gv[3]);   // g[q^3]
        float r1 = __shfl_xor(s1, 4);
        float r2 = __shfl_xor(s2, 8);
        float r3 = __shfl_xor(s3, 12);
        float iG = (q == 0) ? own : (q == 1) ? r1 : (q == 2) ? r2 : r3;
        float fG = (q == 0) ? r1 : (q == 1) ? own : (q == 2) ? r3 : r2;
        float cG = (q == 0) ? r2 : (q == 1) ? r3 : (q == 2) ? own : r1;
        float oG = (q == 0) ? r3 : (q == 1) ? r2 : (q == 2) ? r1 : own;

        // ---- cell update (1 cell per lane) ----
        float ig = 1.f / (1.f + __expf(-iG));
        float fg = 1.f / (1.f + __expf(-fG));
        float cc = tanhf(cG);
        float og = 1.f / (1.f + __expf(-oG));
        float cn = fg * c_reg + ig * cc;
        float hv = og * tanhf(cn);
        c_reg = cn;

        // ---- pack 4 units of my sample via butterfly over jj (verified R10) ----
        unsigned u = (unsigned)f2bf(hv);
        unsigned w = (unsigned)__shfl_xor((int)u, 1);
        unsigned pair = (jj & 1) ? (w | (u << 16)) : (u | (w << 16));
        unsigned p2 = (unsigned)__shfl_xor((int)pair, 2);
        unsigned long long v64 = (jj & 2)
            ? ((unsigned long long)p2 | ((unsigned long long)pair << 32))
            : ((unsigned long long)pair | ((unsigned long long)p2 << 32));
        // TRANSPOSED store: wave's 16 stores = one contiguous 128B line
        if (jj == 0)
            __hip_atomic_store((unsigned long long*)hout + (wgh << 5) + s32,
                               v64, __ATOMIC_RELAXED, __HIP_MEMORY_SCOPE_AGENT);

        // ---- release: per-wave drain (1 line) + per-wave flag ----
        asm volatile("s_waitcnt vmcnt(0)" ::: "memory");
        if (lane == 0)
            __hip_atomic_store(&flagB[(wgh << 1) + wv], (unsigned)(t + 1),
                               __ATOMIC_RELAXED, __HIP_MEMORY_SCOPE_AGENT);

        // ---- post-arrive (off critical path): out stores + next input GEMM ----
        out[((size_t)t << 15) + ((size_t)samp << 9) + j0 + jj] = hv;
        if (t == T_STEPS - 1) {
            size_t base = (size_t)T_STEPS << 15;
            out[base + ((size_t)samp << 9) + j0 + jj] = hv;
            out[base + (1 << 15) + ((size_t)samp << 9) + j0 + jj] = cn;
        }
        if (t + 1 < T_STEPS) {
            const bf16x8* xa = (const bf16x8*)A1 + ((size_t)(((t + 1) << 6) + arow) << 7) + kg;
            acc0 = (f32x4){0.f, 0.f, 0.f, 0.f}; acc1 = acc0; acc2 = acc0; acc3 = acc0;
#pragma unroll
            for (int kk = 0; kk < 32; ++kk) {
                bf16x8 a = xa[kk << 2];
                bf16x8 b = W1L[(kk << 6) + lane];
                f32x4& ac = (kk & 3) == 0 ? acc0 : (kk & 3) == 1 ? acc1 : (kk & 3) == 2 ? acc2 : acc3;
                ac = __builtin_amdgcn_mfma_f32_16x16x32_bf16(a, b, ac, 0, 0, 0);
            }
        }
    }
}

// ---------------- launch ----------------
extern "C" void kernel_launch(void* const* d_in, const int* in_sizes, int n_in,
                              void* d_out, int out_size, void* d_ws, size_t ws_size,
                              hipStream_t stream) {
    const float* x    = (const float*)d_in[0];
    const float* h0   = (const float*)d_in[1];
    const float* c0   = (const float*)d_in[2];
    const float* coef = (const float*)d_in[3];
    const float* Wi   = (const float*)d_in[4];
    const float* bi   = (const float*)d_in[5];
    const float* Wh   = (const float*)d_in[6];
    const float* bh   = (const float*)d_in[7];
    float* out = (float*)d_out;

    char* ws = (char*)d_ws;
    bf16*   W2T     = (bf16*)(ws);                                   // 8 MB
    bf16*   W1T     = (bf16*)(ws + (8u  << 20));                     // 4 MB
    bf16*   A1      = (bf16*)(ws + (12u << 20));                     // 16 MB
    float*  biasmix = (float*)(ws + (28u << 20));                    // 512 KB
    bf16*   h_buf   = (bf16*)(ws + (28u << 20) + (512u << 10));      // 512 KB (2x8x32KB)
    unsigned* flags = (unsigned*)(ws + (29u << 20));                 // 2 KB

    prep_w2t <<<16384, 256, 0, stream>>>(Wh, W2T);
    prep_w1t <<< 8192, 256, 0, stream>>>(Wi, W1T);
    prep_a1  <<<32768, 256, 0, stream>>>(x, coef, A1);
    prep_bias<<<  512, 256, 0, stream>>>(coef, bi, bh, biasmix);
    prep_h0  <<<  128, 256, 0, stream>>>(h0, h_buf, flags);

    void* args[] = {(void*)&W2T, (void*)&W1T, (void*)&A1, (void*)&biasmix,
                    (void*)&h_buf, (void*)&coef, (void*)&c0, (void*)&out, (void*)&flags};
    hipLaunchCooperativeKernel((void*)lstm_rec, dim3(NWG), dim3(128), args, 0, stream);
}

// Round 14
// 754.173 us; speedup vs baseline: 1.3847x; 1.2280x over previous
//
#include <hip/hip_runtime.h>
#include <hip/hip_bf16.h>

typedef __hip_bfloat16 bf16;
typedef __attribute__((ext_vector_type(8))) short bf16x8;
typedef __attribute__((ext_vector_type(4))) short bf16x4;
typedef __attribute__((ext_vector_type(4))) float f32x4;
typedef __attribute__((ext_vector_type(2))) unsigned long long u64x2;

#define T_STEPS 128
#define NWG 256        // 2 halves x 128 WGs, 128 threads (2 waves) each
#define NFLAGS 512     // 2 halves x 256 per-wave flags
#define ZSLOTS 8
// B=64, I=256, H=512, E=4, G=2048. R14 deltas vs verified R13:
// (1) h-frag loads are AGENT-scope atomic loads (LLC-direct, bypass L1/L2) ->
//     no stale-L2 hazard -> the every-8-step rendezvous + buffer_inv is GONE;
//     the step loop now contains ZERO __syncthreads.
// (2) only wave 0 polls the LLC flags; wave 1 waits on an LDS mailbox.
// (3) release chain (sc1 h stores -> vmcnt(0) -> per-wave flag) verbatim R13.

__device__ inline unsigned short f2bf(float f) {
    bf16 b = __float2bfloat16(f);
    return *reinterpret_cast<unsigned short*>(&b);
}

// ---------------- prep kernels (verbatim R13) ----------------

// W2T[o][e*512+hh] = Wh[e][o][hh]   (bf16, [2048][2048])
__global__ void prep_w2t(const float* __restrict__ Wh, bf16* __restrict__ W2T) {
    int idx = blockIdx.x * 256 + threadIdx.x;          // 2048*2048
    int o = idx >> 11, k = idx & 2047;
    int e = k >> 9, hh = k & 511;
    W2T[idx] = __float2bfloat16(Wh[((size_t)((e << 11) + o) << 9) + hh]);
}

// W1T[o][e*256+i] = Wi[e][o][i]     (bf16, [2048][1024])
__global__ void prep_w1t(const float* __restrict__ Wi, bf16* __restrict__ W1T) {
    int idx = blockIdx.x * 256 + threadIdx.x;          // 2048*1024
    int o = idx >> 10, k = idx & 1023;
    int e = k >> 8, i = k & 255;
    W1T[idx] = __float2bfloat16(Wi[((size_t)((e << 11) + o) << 8) + i]);
}

// A1[t*64+b][e*256+i] = coef[b][e] * x[t][b][i]   (bf16, [8192][1024])
__global__ void prep_a1(const float* __restrict__ x, const float* __restrict__ coef,
                        bf16* __restrict__ A1) {
    int idx = blockIdx.x * 256 + threadIdx.x;          // 8192*1024
    int row = idx >> 10, k = idx & 1023;
    int b = row & 63;
    int e = k >> 8, i = k & 255;
    A1[idx] = __float2bfloat16(coef[(b << 2) + e] * x[((size_t)row << 8) + i]);
}

// biasmix[b][o] = sum_e coef[b][e]*(bi[e][o]+bh[e][o])   (f32, [64][2048])
__global__ void prep_bias(const float* __restrict__ coef, const float* __restrict__ bi,
                          const float* __restrict__ bh, float* __restrict__ biasmix) {
    int idx = blockIdx.x * 256 + threadIdx.x;          // 64*2048
    int b = idx >> 11, o = idx & 2047;
    float s = 0.f;
#pragma unroll
    for (int e = 0; e < 4; ++e)
        s += coef[(b << 2) + e] * (bi[(e << 11) + o] + bh[(e << 11) + o]);
    biasmix[idx] = s;
}

// h0 -> slot 0 per half, transposed hq[ug][samp32][uu]; zero the 512 flags
__global__ void prep_h0(const float* __restrict__ h0, bf16* __restrict__ hbuf,
                        unsigned* __restrict__ flags) {
    int idx = blockIdx.x * 256 + threadIdx.x;          // 64*512 = 32768
    if (idx < NFLAGS) flags[idx] = 0u;
    int s = idx >> 9, u = idx & 511;
    int half = s >> 5, s32 = s & 31;
    int ug = u >> 2, uu = u & 3;
    hbuf[(size_t)half * (ZSLOTS * 16384) + ((ug << 5) + s32) * 4 + uu] =
        __float2bfloat16(h0[((size_t)s << 9) + u]);
}

// ---------------- main recurrent kernel ----------------
__launch_bounds__(128, 1)
__global__ void lstm_rec(const bf16* __restrict__ W2T, const bf16* __restrict__ W1T,
                         const bf16* __restrict__ A1, const float* __restrict__ biasmix,
                         bf16* h_buf, const float* __restrict__ coef,
                         const float* __restrict__ c0, float* __restrict__ out,
                         unsigned* __restrict__ flags) {
    __shared__ bf16x8 W2L[4 * 16 * 64];   // [e][kk][lane] fragments, 64KB
    __shared__ bf16x8 W1L[32 * 64];       // [kk][lane] fragments, 32KB
    __shared__ unsigned hmail;            // wave0 -> wave1 epoch mailbox

    const int wg   = blockIdx.x;      // 0..255
    const int half = wg >> 7;         // 0,1: samples half*32 .. +31
    const int wgh  = wg & 127;        // WG within half; owns units j0..j0+3
    const int j0   = wgh << 2;
    const int tid  = threadIdx.x;     // 0..127
    const int lane = tid & 63;
    const int wv   = tid >> 6;        // wave 0,1 -> local sample rows 16*wv..+15

    const int rlo  = lane & 15;       // MFMA col within 16: rlo = q*4 + jj
    const int kg   = lane >> 4;       // k-group / C row-quad
    const int q    = rlo >> 2;        // gate index of this lane's col
    const int jj   = rlo & 3;         // unit-within-WG
    const int s32  = (wv << 4) + (kg << 2) + q;     // local sample of my cell
    const int samp = (half << 5) + s32;             // global sample
    const int arow = (half << 5) + (wv << 4) + rlo; // global A-row this lane loads
    const int a32  = (wv << 4) + rlo;               // local A-row (h buffer)
    const int o_ln = (q << 9) + j0 + jj;            // this lane's gate column

    // ---- build LDS weight fragments (verbatim R13) ----
    for (int g = tid; g < 4096; g += 128) {
        int e = g >> 10, kk = (g >> 6) & 15, l = g & 63;
        int rl = l & 15, kgg = l >> 4;
        int o = ((rl >> 2) << 9) + j0 + (rl & 3);
        W2L[g] = *(const bf16x8*)(W2T + ((size_t)o << 11) + (e << 9) + (kk << 5) + (kgg << 3));
    }
    for (int g = tid; g < 2048; g += 128) {
        int kk = g >> 6, l = g & 63;
        int rl = l & 15, kgg = l >> 4;
        int o = ((rl >> 2) << 9) + j0 + (rl & 3);
        W1L[g] = *(const bf16x8*)(W1T + ((size_t)o << 10) + (kk << 5) + (kgg << 3));
    }
    if (tid == 0) hmail = 0u;

    // ---- per-lane constants in registers ----
    float bias_r[4];
    float4 cw[4];
#pragma unroll
    for (int r = 0; r < 4; ++r) {
        int row = (half << 5) + (wv << 4) + (kg << 2) + r;   // global sample row
        bias_r[r] = biasmix[((size_t)row << 11) + o_ln];
        cw[r] = *(const float4*)(coef + (row << 2));
    }
    float c_reg = c0[((size_t)samp << 9) + j0 + jj];

    // per-half h buffer (8 slots x 16384 elems) and flag block
    bf16* hB = h_buf + (size_t)half * (ZSLOTS * 16384);
    unsigned* flagB = flags + (half << 8);

    __syncthreads();   // LDS weights + mailbox ready (only barrier in kernel)

    f32x4 acc0, acc1, acc2, acc3;   // input-part accumulators (overlap slot)
    {
        const bf16x8* xa = (const bf16x8*)A1 + ((size_t)arow << 7) + kg;
        acc0 = (f32x4){0.f, 0.f, 0.f, 0.f}; acc1 = acc0; acc2 = acc0; acc3 = acc0;
#pragma unroll
        for (int kk = 0; kk < 32; ++kk) {
            bf16x8 a = xa[kk << 2];
            bf16x8 b = W1L[(kk << 6) + lane];
            f32x4& ac = (kk & 3) == 0 ? acc0 : (kk & 3) == 1 ? acc1 : (kk & 3) == 2 ? acc2 : acc3;
            ac = __builtin_amdgcn_mfma_f32_16x16x32_bf16(a, b, ac, 0, 0, 0);
        }
    }

    float spin = 1.0f;   // FMA-backoff accumulator (kept live via asm sink)

    for (int t = 0; t < T_STEPS; ++t) {
        // ---- wait for epoch t: wave0 polls LLC flags; wave1 waits mailbox ----
        if (t) {
            const unsigned tt = (unsigned)t;
            if (wv == 0) {
                const unsigned long long* f64 = (const unsigned long long*)flagB + (lane << 1);
                while (true) {
                    unsigned long long v0 = __hip_atomic_load(f64 + 0, __ATOMIC_RELAXED, __HIP_MEMORY_SCOPE_AGENT);
                    unsigned long long v1 = __hip_atomic_load(f64 + 1, __ATOMIC_RELAXED, __HIP_MEMORY_SCOPE_AGENT);
                    if ((unsigned)v0 >= tt && (unsigned)(v0 >> 32) >= tt &&
                        (unsigned)v1 >= tt && (unsigned)(v1 >> 32) >= tt) break;
#pragma unroll
                    for (int i = 0; i < 64; ++i)       // ~256cy dependent chain
                        spin = __builtin_fmaf(spin, 1.0000001f, 1e-30f);
                    asm volatile("" :: "v"(spin));      // keep live (no DCE)
                }
                if (lane == 0)
                    __hip_atomic_store(&hmail, tt, __ATOMIC_RELEASE, __HIP_MEMORY_SCOPE_WORKGROUP);
            } else {
                while (__hip_atomic_load(&hmail, __ATOMIC_ACQUIRE, __HIP_MEMORY_SCOPE_WORKGROUP) < tt) {
#pragma unroll
                    for (int i = 0; i < 16; ++i)
                        spin = __builtin_fmaf(spin, 1.0000001f, 1e-30f);
                    asm volatile("" :: "v"(spin));
                }
            }
        }

        // h slots transposed: hq[ug=wgh][samp32], 8B entries, 32KB/slot
        const bf16* hin  = hB + (((size_t)t & (ZSLOTS - 1)) << 14);
        bf16*       hout = hB + (((size_t)(t + 1) & (ZSLOTS - 1)) << 14);

        // ---- hidden GEMM: 32 LLC-direct 8B atomic loads (no L2 staleness,
        //      no inv needed), then 4-expert MFMA ----
        f32x4 e0 = {0.f, 0.f, 0.f, 0.f}, e1 = e0, e2 = e0, e3 = e0;
        {
            const unsigned long long* hq = (const unsigned long long*)hin;
            bf16x8 areg[16];
#pragma unroll
            for (int kk = 0; kk < 16; ++kk) {
                int ug = (kk << 3) + (kg << 1);
                unsigned long long lo = __hip_atomic_load(hq + (ug << 5) + a32,
                                                          __ATOMIC_RELAXED, __HIP_MEMORY_SCOPE_AGENT);
                unsigned long long hi = __hip_atomic_load(hq + ((ug + 1) << 5) + a32,
                                                          __ATOMIC_RELAXED, __HIP_MEMORY_SCOPE_AGENT);
                u64x2 t2; t2[0] = lo; t2[1] = hi;
                areg[kk] = __builtin_bit_cast(bf16x8, t2);
            }
#pragma unroll
            for (int kk = 0; kk < 16; ++kk) {
                e0 = __builtin_amdgcn_mfma_f32_16x16x32_bf16(areg[kk], W2L[(kk << 6) + lane       ], e0, 0, 0, 0);
                e1 = __builtin_amdgcn_mfma_f32_16x16x32_bf16(areg[kk], W2L[(kk << 6) + lane + 1024], e1, 0, 0, 0);
                e2 = __builtin_amdgcn_mfma_f32_16x16x32_bf16(areg[kk], W2L[(kk << 6) + lane + 2048], e2, 0, 0, 0);
                e3 = __builtin_amdgcn_mfma_f32_16x16x32_bf16(areg[kk], W2L[(kk << 6) + lane + 3072], e3, 0, 0, 0);
            }
        }

        // ---- epilogue in registers: g = sum_e coef*acc_e + xg + bias ----
        f32x4 gv;
        {
            f32x4 xin = (acc0 + acc1) + (acc2 + acc3);
#pragma unroll
            for (int r = 0; r < 4; ++r)
                gv[r] = e0[r] * cw[r].x + e1[r] * cw[r].y + e2[r] * cw[r].z + e3[r] * cw[r].w
                      + xin[r] + bias_r[r];
        }

        // ---- gate exchange among 4 gate-lanes (xor 4/8/12) — verified R10 ----
        const bool b0 = (q & 1), b1 = (q & 2);
        float own = b1 ? (b0 ? gv[3] : gv[2]) : (b0 ? gv[1] : gv[0]);   // g[q]
        float s1  = b1 ? (b0 ? gv[2] : gv[3]) : (b0 ? gv[0] : gv[1]);   // g[q^1]
        float s2  = b1 ? (b0 ? gv[1] : gv[0]) : (b0 ? gv[3] : gv[2]);   // g[q^2]
        float s3  = b1 ? (b0 ? gv[0] : gv[1]) : (b0 ? gv[2] : gv[3]);   // g[q^3]
        float r1 = __shfl_xor(s1, 4);
        float r2 = __shfl_xor(s2, 8);
        float r3 = __shfl_xor(s3, 12);
        float iG = (q == 0) ? own : (q == 1) ? r1 : (q == 2) ? r2 : r3;
        float fG = (q == 0) ? r1 : (q == 1) ? own : (q == 2) ? r3 : r2;
        float cG = (q == 0) ? r2 : (q == 1) ? r3 : (q == 2) ? own : r1;
        float oG = (q == 0) ? r3 : (q == 1) ? r2 : (q == 2) ? r1 : own;

        // ---- cell update (1 cell per lane) ----
        float ig = 1.f / (1.f + __expf(-iG));
        float fg = 1.f / (1.f + __expf(-fG));
        float cc = tanhf(cG);
        float og = 1.f / (1.f + __expf(-oG));
        float cn = fg * c_reg + ig * cc;
        float hv = og * tanhf(cn);
        c_reg = cn;

        // ---- pack 4 units of my sample via butterfly over jj (verified R10) ----
        unsigned u = (unsigned)f2bf(hv);
        unsigned w = (unsigned)__shfl_xor((int)u, 1);
        unsigned pair = (jj & 1) ? (w | (u << 16)) : (u | (w << 16));
        unsigned p2 = (unsigned)__shfl_xor((int)pair, 2);
        unsigned long long v64 = (jj & 2)
            ? ((unsigned long long)p2 | ((unsigned long long)pair << 32))
            : ((unsigned long long)pair | ((unsigned long long)p2 << 32));
        // TRANSPOSED store: wave's 16 stores = one contiguous 128B line
        if (jj == 0)
            __hip_atomic_store((unsigned long long*)hout + (wgh << 5) + s32,
                               v64, __ATOMIC_RELAXED, __HIP_MEMORY_SCOPE_AGENT);

        // ---- release: per-wave drain (1 line) + per-wave flag ----
        asm volatile("s_waitcnt vmcnt(0)" ::: "memory");
        if (lane == 0)
            __hip_atomic_store(&flagB[(wgh << 1) + wv], (unsigned)(t + 1),
                               __ATOMIC_RELAXED, __HIP_MEMORY_SCOPE_AGENT);

        // ---- post-arrive (off critical path): out stores + next input GEMM ----
        out[((size_t)t << 15) + ((size_t)samp << 9) + j0 + jj] = hv;
        if (t == T_STEPS - 1) {
            size_t base = (size_t)T_STEPS << 15;
            out[base + ((size_t)samp << 9) + j0 + jj] = hv;
            out[base + (1 << 15) + ((size_t)samp << 9) + j0 + jj] = cn;
        }
        if (t + 1 < T_STEPS) {
            const bf16x8* xa = (const bf16x8*)A1 + ((size_t)(((t + 1) << 6) + arow) << 7) + kg;
            acc0 = (f32x4){0.f, 0.f, 0.f, 0.f}; acc1 = acc0; acc2 = acc0; acc3 = acc0;
#pragma unroll
            for (int kk = 0; kk < 32; ++kk) {
                bf16x8 a = xa[kk << 2];
                bf16x8 b = W1L[(kk << 6) + lane];
                f32x4& ac = (kk & 3) == 0 ? acc0 : (kk & 3) == 1 ? acc1 : (kk & 3) == 2 ? acc2 : acc3;
                ac = __builtin_amdgcn_mfma_f32_16x16x32_bf16(a, b, ac, 0, 0, 0);
            }
        }
    }
}

// ---------------- launch (verbatim R13) ----------------
extern "C" void kernel_launch(void* const* d_in, const int* in_sizes, int n_in,
                              void* d_out, int out_size, void* d_ws, size_t ws_size,
                              hipStream_t stream) {
    const float* x    = (const float*)d_in[0];
    const float* h0   = (const float*)d_in[1];
    const float* c0   = (const float*)d_in[2];
    const float* coef = (const float*)d_in[3];
    const float* Wi   = (const float*)d_in[4];
    const float* bi   = (const float*)d_in[5];
    const float* Wh   = (const float*)d_in[6];
    const float* bh   = (const float*)d_in[7];
    float* out = (float*)d_out;

    char* ws = (char*)d_ws;
    bf16*   W2T     = (bf16*)(ws);                                   // 8 MB
    bf16*   W1T     = (bf16*)(ws + (8u  << 20));                     // 4 MB
    bf16*   A1      = (bf16*)(ws + (12u << 20));                     // 16 MB
    float*  biasmix = (float*)(ws + (28u << 20));                    // 512 KB
    bf16*   h_buf   = (bf16*)(ws + (28u << 20) + (512u << 10));      // 512 KB (2x8x32KB)
    unsigned* flags = (unsigned*)(ws + (29u << 20));                 // 2 KB

    prep_w2t <<<16384, 256, 0, stream>>>(Wh, W2T);
    prep_w1t <<< 8192, 256, 0, stream>>>(Wi, W1T);
    prep_a1  <<<32768, 256, 0, stream>>>(x, coef, A1);
    prep_bias<<<  512, 256, 0, stream>>>(coef, bi, bh, biasmix);
    prep_h0  <<<  128, 256, 0, stream>>>(h0, h_buf, flags);

    void* args[] = {(void*)&W2T, (void*)&W1T, (void*)&A1, (void*)&biasmix,
                    (void*)&h_buf, (void*)&coef, (void*)&c0, (void*)&out, (void*)&flags};
    hipLaunchCooperativeKernel((void*)lstm_rec, dim3(NWG), dim3(128), args, 0, stream);
}

// Round 16
// 742.820 us; speedup vs baseline: 1.4059x; 1.0153x over previous
//
#include <hip/hip_runtime.h>
#include <hip/hip_bf16.h>

typedef __hip_bfloat16 bf16;
typedef __attribute__((ext_vector_type(8))) short bf16x8;
typedef __attribute__((ext_vector_type(4))) float f32x4;
typedef __attribute__((ext_vector_type(2))) unsigned long long u64x2;

#define T_STEPS 128
#define NWG 256        // 256 WGs x 128 threads — R13/R14's PROVEN launch config
#define NFLAGS 512     // 4 quarters x 128 per-wave flags
#define ZSLOTS 8
// B=64, I=256, H=512, E=4, G=2048. R16: R15's 4-quarter domain shrink inside
// R14's proven launch geometry. Wave wv of WG wg serves quarter
// qt=(wg>>7)*2+wv (samples 16qt..+15), units 4*(wg&127)..+3. Both waves share
// the WG's read-only LDS weights; each wave is an independent 128-wave sync
// domain: poll = ONE u64/lane (128 flags), release = ONE 128B h line + one
// flag, no intra-WG coordination. Per-wave math + sync skeleton verbatim R14.

__device__ inline unsigned short f2bf(float f) {
    bf16 b = __float2bfloat16(f);
    return *reinterpret_cast<unsigned short*>(&b);
}

// ---------------- prep kernels ----------------

// W2T[o][e*512+hh] = Wh[e][o][hh]   (bf16, [2048][2048])
__global__ void prep_w2t(const float* __restrict__ Wh, bf16* __restrict__ W2T) {
    int idx = blockIdx.x * 256 + threadIdx.x;          // 2048*2048
    int o = idx >> 11, k = idx & 2047;
    int e = k >> 9, hh = k & 511;
    W2T[idx] = __float2bfloat16(Wh[((size_t)((e << 11) + o) << 9) + hh]);
}

// W1T[o][e*256+i] = Wi[e][o][i]     (bf16, [2048][1024])
__global__ void prep_w1t(const float* __restrict__ Wi, bf16* __restrict__ W1T) {
    int idx = blockIdx.x * 256 + threadIdx.x;          // 2048*1024
    int o = idx >> 10, k = idx & 1023;
    int e = k >> 8, i = k & 255;
    W1T[idx] = __float2bfloat16(Wi[((size_t)((e << 11) + o) << 8) + i]);
}

// A1[t*64+b][e*256+i] = coef[b][e] * x[t][b][i]   (bf16, [8192][1024])
__global__ void prep_a1(const float* __restrict__ x, const float* __restrict__ coef,
                        bf16* __restrict__ A1) {
    int idx = blockIdx.x * 256 + threadIdx.x;          // 8192*1024
    int row = idx >> 10, k = idx & 1023;
    int b = row & 63;
    int e = k >> 8, i = k & 255;
    A1[idx] = __float2bfloat16(coef[(b << 2) + e] * x[((size_t)row << 8) + i]);
}

// biasmix[b][o] = sum_e coef[b][e]*(bi[e][o]+bh[e][o])   (f32, [64][2048])
__global__ void prep_bias(const float* __restrict__ coef, const float* __restrict__ bi,
                          const float* __restrict__ bh, float* __restrict__ biasmix) {
    int idx = blockIdx.x * 256 + threadIdx.x;          // 64*2048
    int b = idx >> 11, o = idx & 2047;
    float s = 0.f;
#pragma unroll
    for (int e = 0; e < 4; ++e)
        s += coef[(b << 2) + e] * (bi[(e << 11) + o] + bh[(e << 11) + o]);
    biasmix[idx] = s;
}

// h0 -> slot 0 per quarter, transposed hq[ug][s16][uu]; zero the 512 flags
__global__ void prep_h0(const float* __restrict__ h0, bf16* __restrict__ hbuf,
                        unsigned* __restrict__ flags) {
    int idx = blockIdx.x * 256 + threadIdx.x;          // 64*512 = 32768
    if (idx < NFLAGS) flags[idx] = 0u;
    int s = idx >> 9, u = idx & 511;
    int qt = s >> 4, s16 = s & 15;
    int ug = u >> 2, uu = u & 3;
    hbuf[(size_t)qt * (ZSLOTS * 8192) + (((ug << 4) + s16) << 2) + uu] =
        __float2bfloat16(h0[((size_t)s << 9) + u]);
}

// ---------------- main recurrent kernel ----------------
__launch_bounds__(128, 1)
__global__ void lstm_rec(const bf16* __restrict__ W2T, const bf16* __restrict__ W1T,
                         const bf16* __restrict__ A1, const float* __restrict__ biasmix,
                         bf16* h_buf, const float* __restrict__ coef,
                         const float* __restrict__ c0, float* __restrict__ out,
                         unsigned* __restrict__ flags) {
    __shared__ bf16x8 W2L[4 * 16 * 64];   // [e][kk][lane] fragments, 64KB
    __shared__ bf16x8 W1L[32 * 64];       // [kk][lane] fragments, 32KB

    const int wg   = blockIdx.x;      // 0..255
    const int wgh  = wg & 127;        // owns units j0..j0+3 (both waves)
    const int j0   = wgh << 2;
    const int tid  = threadIdx.x;     // 0..127
    const int lane = tid & 63;
    const int wv   = tid >> 6;        // wave 0,1
    const int qt   = ((wg >> 7) << 1) + wv;   // this WAVE's quarter 0..3

    const int rlo  = lane & 15;       // MFMA col within 16: rlo = q*4 + jj
    const int kg   = lane >> 4;       // k-group / C row-quad
    const int q    = rlo >> 2;        // gate index of this lane's col
    const int jj   = rlo & 3;         // unit-within-WG
    const int s16  = (kg << 2) + q;   // local sample of my cell
    const int samp = (qt << 4) + s16; // global sample
    const int arow = (qt << 4) + rlo; // global A1 row this lane loads
    const int o_ln = (q << 9) + j0 + jj;   // this lane's gate column

    // ---- build LDS weight fragments (verbatim R14; shared by both waves) ----
    for (int g = tid; g < 4096; g += 128) {
        int e = g >> 10, kk = (g >> 6) & 15, l = g & 63;
        int rl = l & 15, kgg = l >> 4;
        int o = ((rl >> 2) << 9) + j0 + (rl & 3);
        W2L[g] = *(const bf16x8*)(W2T + ((size_t)o << 11) + (e << 9) + (kk << 5) + (kgg << 3));
    }
    for (int g = tid; g < 2048; g += 128) {
        int kk = g >> 6, l = g & 63;
        int rl = l & 15, kgg = l >> 4;
        int o = ((rl >> 2) << 9) + j0 + (rl & 3);
        W1L[g] = *(const bf16x8*)(W1T + ((size_t)o << 10) + (kk << 5) + (kgg << 3));
    }

    // ---- per-lane constants in registers ----
    float bias_r[4];
    float4 cw[4];
#pragma unroll
    for (int r = 0; r < 4; ++r) {
        int row = (qt << 4) + (kg << 2) + r;   // global sample row of C quad
        bias_r[r] = biasmix[((size_t)row << 11) + o_ln];
        cw[r] = *(const float4*)(coef + (row << 2));
    }
    float c_reg = c0[((size_t)samp << 9) + j0 + jj];

    // per-quarter h buffer (8 slots x 8192 elems = 16KB/slot) and flag block
    bf16* hB = h_buf + (size_t)qt * (ZSLOTS * 8192);
    unsigned* flagB = flags + (qt << 7);

    __syncthreads();   // LDS weights ready (only barrier in the kernel)

    f32x4 acc0, acc1, acc2, acc3;   // input-part accumulators (overlap slot)
    {
        const bf16x8* xa = (const bf16x8*)A1 + ((size_t)arow << 7) + kg;
        acc0 = (f32x4){0.f, 0.f, 0.f, 0.f}; acc1 = acc0; acc2 = acc0; acc3 = acc0;
#pragma unroll
        for (int kk = 0; kk < 32; ++kk) {
            bf16x8 a = xa[kk << 2];
            bf16x8 b = W1L[(kk << 6) + lane];
            f32x4& ac = (kk & 3) == 0 ? acc0 : (kk & 3) == 1 ? acc1 : (kk & 3) == 2 ? acc2 : acc3;
            ac = __builtin_amdgcn_mfma_f32_16x16x32_bf16(a, b, ac, 0, 0, 0);
        }
    }

    float spin = 1.0f;   // FMA-backoff accumulator (kept live via asm sink)

    for (int t = 0; t < T_STEPS; ++t) {
        // ---- wait for epoch t: ONE u64 flag load per lane (128 flags/qt) ----
        if (t) {
            const unsigned long long* f64 = (const unsigned long long*)flagB + lane;
            const unsigned tt = (unsigned)t;
            while (true) {
                unsigned long long v = __hip_atomic_load(f64, __ATOMIC_RELAXED,
                                                         __HIP_MEMORY_SCOPE_AGENT);
                if ((unsigned)v >= tt && (unsigned)(v >> 32) >= tt) break;
#pragma unroll
                for (int i = 0; i < 64; ++i)           // ~256cy dependent chain
                    spin = __builtin_fmaf(spin, 1.0000001f, 1e-30f);
                asm volatile("" :: "v"(spin));          // keep live (no DCE)
            }
        }

        // h slots transposed: hq[ug=wgh][s16], 8B entries, 16KB/slot
        const bf16* hin  = hB + (((size_t)t & (ZSLOTS - 1)) << 13);
        bf16*       hout = hB + (((size_t)(t + 1) & (ZSLOTS - 1)) << 13);

        // ---- hidden GEMM: 32 LLC-direct 8B atomic loads, 4-expert MFMA ----
        f32x4 e0 = {0.f, 0.f, 0.f, 0.f}, e1 = e0, e2 = e0, e3 = e0;
        {
            const unsigned long long* hq = (const unsigned long long*)hin;
            bf16x8 areg[16];
#pragma unroll
            for (int kk = 0; kk < 16; ++kk) {
                int ug = (kk << 3) + (kg << 1);
                unsigned long long lo = __hip_atomic_load(hq + (ug << 4) + rlo,
                                                          __ATOMIC_RELAXED, __HIP_MEMORY_SCOPE_AGENT);
                unsigned long long hi = __hip_atomic_load(hq + ((ug + 1) << 4) + rlo,
                                                          __ATOMIC_RELAXED, __HIP_MEMORY_SCOPE_AGENT);
                u64x2 t2; t2[0] = lo; t2[1] = hi;
                areg[kk] = __builtin_bit_cast(bf16x8, t2);
            }
#pragma unroll
            for (int kk = 0; kk < 16; ++kk) {
                e0 = __builtin_amdgcn_mfma_f32_16x16x32_bf16(areg[kk], W2L[(kk << 6) + lane       ], e0, 0, 0, 0);
                e1 = __builtin_amdgcn_mfma_f32_16x16x32_bf16(areg[kk], W2L[(kk << 6) + lane + 1024], e1, 0, 0, 0);
                e2 = __builtin_amdgcn_mfma_f32_16x16x32_bf16(areg[kk], W2L[(kk << 6) + lane + 2048], e2, 0, 0, 0);
                e3 = __builtin_amdgcn_mfma_f32_16x16x32_bf16(areg[kk], W2L[(kk << 6) + lane + 3072], e3, 0, 0, 0);
            }
        }

        // ---- epilogue in registers: g = sum_e coef*acc_e + xg + bias ----
        f32x4 gv;
        {
            f32x4 xin = (acc0 + acc1) + (acc2 + acc3);
#pragma unroll
            for (int r = 0; r < 4; ++r)
                gv[r] = e0[r] * cw[r].x + e1[r] * cw[r].y + e2[r] * cw[r].z + e3[r] * cw[r].w
                      + xin[r] + bias_r[r];
        }

        // ---- gate exchange among 4 gate-lanes (xor 4/8/12) — verified R10 ----
        const bool b0 = (q & 1), b1 = (q & 2);
        float own = b1 ? (b0 ? gv[3] : gv[2]) : (b0 ? gv[1] : gv[0]);   // g[q]
        float s1  = b1 ? (b0 ? gv[2] : gv[3]) : (b0 ? gv[0] : gv[1]);   // g[q^1]
        float s2  = b1 ? (b0 ? gv[1] : gv[0]) : (b0 ? gv[3] : gv[2]);   // g[q^2]
        float s3  = b1 ? (b0 ? gv[0] : gv[1]) : (b0 ? gv[2] : gv[3]);   // g[q^3]
        float r1 = __shfl_xor(s1, 4);
        float r2 = __shfl_xor(s2, 8);
        float r3 = __shfl_xor(s3, 12);
        float iG = (q == 0) ? own : (q == 1) ? r1 : (q == 2) ? r2 : r3;
        float fG = (q == 0) ? r1 : (q == 1) ? own : (q == 2) ? r3 : r2;
        float cG = (q == 0) ? r2 : (q == 1) ? r3 : (q == 2) ? own : r1;
        float oG = (q == 0) ? r3 : (q == 1) ? r2 : (q == 2) ? r1 : own;

        // ---- cell update (1 cell per lane) ----
        float ig = 1.f / (1.f + __expf(-iG));
        float fg = 1.f / (1.f + __expf(-fG));
        float cc = tanhf(cG);
        float og = 1.f / (1.f + __expf(-oG));
        float cn = fg * c_reg + ig * cc;
        float hv = og * tanhf(cn);
        c_reg = cn;

        // ---- pack 4 units of my sample via butterfly over jj (verified R10) ----
        unsigned u = (unsigned)f2bf(hv);
        unsigned w = (unsigned)__shfl_xor((int)u, 1);
        unsigned pair = (jj & 1) ? (w | (u << 16)) : (u | (w << 16));
        unsigned p2 = (unsigned)__shfl_xor((int)pair, 2);
        unsigned long long v64 = (jj & 2)
            ? ((unsigned long long)p2 | ((unsigned long long)pair << 32))
            : ((unsigned long long)pair | ((unsigned long long)p2 << 32));
        // TRANSPOSED store: wave's 16 stores = ONE contiguous 128B line
        if (jj == 0)
            __hip_atomic_store((unsigned long long*)hout + (wgh << 4) + s16,
                               v64, __ATOMIC_RELAXED, __HIP_MEMORY_SCOPE_AGENT);

        // ---- release: drain (1 line) + single per-wave flag ----
        asm volatile("s_waitcnt vmcnt(0)" ::: "memory");
        if (lane == 0)
            __hip_atomic_store(&flagB[wgh], (unsigned)(t + 1),
                               __ATOMIC_RELAXED, __HIP_MEMORY_SCOPE_AGENT);

        // ---- post-arrive (off critical path): out stores + next input GEMM ----
        out[((size_t)t << 15) + ((size_t)samp << 9) + j0 + jj] = hv;
        if (t == T_STEPS - 1) {
            size_t base = (size_t)T_STEPS << 15;
            out[base + ((size_t)samp << 9) + j0 + jj] = hv;
            out[base + (1 << 15) + ((size_t)samp << 9) + j0 + jj] = cn;
        }
        if (t + 1 < T_STEPS) {
            const bf16x8* xa = (const bf16x8*)A1 + ((size_t)(((t + 1) << 6) + arow) << 7) + kg;
            acc0 = (f32x4){0.f, 0.f, 0.f, 0.f}; acc1 = acc0; acc2 = acc0; acc3 = acc0;
#pragma unroll
            for (int kk = 0; kk < 32; ++kk) {
                bf16x8 a = xa[kk << 2];
                bf16x8 b = W1L[(kk << 6) + lane];
                f32x4& ac = (kk & 3) == 0 ? acc0 : (kk & 3) == 1 ? acc1 : (kk & 3) == 2 ? acc2 : acc3;
                ac = __builtin_amdgcn_mfma_f32_16x16x32_bf16(a, b, ac, 0, 0, 0);
            }
        }
    }
}

// ---------------- launch (geometry verbatim R14) ----------------
extern "C" void kernel_launch(void* const* d_in, const int* in_sizes, int n_in,
                              void* d_out, int out_size, void* d_ws, size_t ws_size,
                              hipStream_t stream) {
    const float* x    = (const float*)d_in[0];
    const float* h0   = (const float*)d_in[1];
    const float* c0   = (const float*)d_in[2];
    const float* coef = (const float*)d_in[3];
    const float* Wi   = (const float*)d_in[4];
    const float* bi   = (const float*)d_in[5];
    const float* Wh   = (const float*)d_in[6];
    const float* bh   = (const float*)d_in[7];
    float* out = (float*)d_out;

    char* ws = (char*)d_ws;
    bf16*   W2T     = (bf16*)(ws);                                   // 8 MB
    bf16*   W1T     = (bf16*)(ws + (8u  << 20));                     // 4 MB
    bf16*   A1      = (bf16*)(ws + (12u << 20));                     // 16 MB
    float*  biasmix = (float*)(ws + (28u << 20));                    // 512 KB
    bf16*   h_buf   = (bf16*)(ws + (28u << 20) + (512u << 10));      // 512 KB (4x8x16KB)
    unsigned* flags = (unsigned*)(ws + (29u << 20));                 // 2 KB

    prep_w2t <<<16384, 256, 0, stream>>>(Wh, W2T);
    prep_w1t <<< 8192, 256, 0, stream>>>(Wi, W1T);
    prep_a1  <<<32768, 256, 0, stream>>>(x, coef, A1);
    prep_bias<<<  512, 256, 0, stream>>>(coef, bi, bh, biasmix);
    prep_h0  <<<  128, 256, 0, stream>>>(h0, h_buf, flags);

    void* args[] = {(void*)&W2T, (void*)&W1T, (void*)&A1, (void*)&biasmix,
                    (void*)&h_buf, (void*)&coef, (void*)&c0, (void*)&out, (void*)&flags};
    hipLaunchCooperativeKernel((void*)lstm_rec, dim3(NWG), dim3(128), args, 0, stream);
}

// Round 18
// 732.226 us; speedup vs baseline: 1.4262x; 1.0145x over previous
//
#include <hip/hip_runtime.h>
#include <hip/hip_bf16.h>

typedef __hip_bfloat16 bf16;
typedef __attribute__((ext_vector_type(8))) short bf16x8;
typedef __attribute__((ext_vector_type(4))) float f32x4;
typedef __attribute__((ext_vector_type(2))) unsigned long long u64x2;

#define T_STEPS 128
#define NWG 256        // 256 WGs x 128 threads — proven launch config
#define NFLAGS 512     // 4 quarters x 128 per-wave flags
#define ZSLOTS 8
// B=64, I=256, H=512, E=4, G=2048. R18 = verified R16 base (743us) + two
// contained tweaks: (1) poll spin 64->24 FMA (finer discovery quantization);
// (2) post-arrive reorder: next-step input GEMM (L2/LLC loads) issued BEFORE
// the HBM out stores. Everything else byte-identical to R16.

__device__ inline unsigned short f2bf(float f) {
    bf16 b = __float2bfloat16(f);
    return *reinterpret_cast<unsigned short*>(&b);
}

// ---------------- prep kernels ----------------

// W2T[o][e*512+hh] = Wh[e][o][hh]   (bf16, [2048][2048])
__global__ void prep_w2t(const float* __restrict__ Wh, bf16* __restrict__ W2T) {
    int idx = blockIdx.x * 256 + threadIdx.x;          // 2048*2048
    int o = idx >> 11, k = idx & 2047;
    int e = k >> 9, hh = k & 511;
    W2T[idx] = __float2bfloat16(Wh[((size_t)((e << 11) + o) << 9) + hh]);
}

// W1T[o][e*256+i] = Wi[e][o][i]     (bf16, [2048][1024])
__global__ void prep_w1t(const float* __restrict__ Wi, bf16* __restrict__ W1T) {
    int idx = blockIdx.x * 256 + threadIdx.x;          // 2048*1024
    int o = idx >> 10, k = idx & 1023;
    int e = k >> 8, i = k & 255;
    W1T[idx] = __float2bfloat16(Wi[((size_t)((e << 11) + o) << 8) + i]);
}

// A1[t*64+b][e*256+i] = coef[b][e] * x[t][b][i]   (bf16, [8192][1024])
__global__ void prep_a1(const float* __restrict__ x, const float* __restrict__ coef,
                        bf16* __restrict__ A1) {
    int idx = blockIdx.x * 256 + threadIdx.x;          // 8192*1024
    int row = idx >> 10, k = idx & 1023;
    int b = row & 63;
    int e = k >> 8, i = k & 255;
    A1[idx] = __float2bfloat16(coef[(b << 2) + e] * x[((size_t)row << 8) + i]);
}

// biasmix[b][o] = sum_e coef[b][e]*(bi[e][o]+bh[e][o])   (f32, [64][2048])
__global__ void prep_bias(const float* __restrict__ coef, const float* __restrict__ bi,
                          const float* __restrict__ bh, float* __restrict__ biasmix) {
    int idx = blockIdx.x * 256 + threadIdx.x;          // 64*2048
    int b = idx >> 11, o = idx & 2047;
    float s = 0.f;
#pragma unroll
    for (int e = 0; e < 4; ++e)
        s += coef[(b << 2) + e] * (bi[(e << 11) + o] + bh[(e << 11) + o]);
    biasmix[idx] = s;
}

// h0 -> slot 0 per quarter, transposed hq[ug][s16][uu]; zero the 512 flags
__global__ void prep_h0(const float* __restrict__ h0, bf16* __restrict__ hbuf,
                        unsigned* __restrict__ flags) {
    int idx = blockIdx.x * 256 + threadIdx.x;          // 64*512 = 32768
    if (idx < NFLAGS) flags[idx] = 0u;
    int s = idx >> 9, u = idx & 511;
    int qt = s >> 4, s16 = s & 15;
    int ug = u >> 2, uu = u & 3;
    hbuf[(size_t)qt * (ZSLOTS * 8192) + (((ug << 4) + s16) << 2) + uu] =
        __float2bfloat16(h0[((size_t)s << 9) + u]);
}

// ---------------- main recurrent kernel ----------------
__launch_bounds__(128, 1)
__global__ void lstm_rec(const bf16* __restrict__ W2T, const bf16* __restrict__ W1T,
                         const bf16* __restrict__ A1, const float* __restrict__ biasmix,
                         bf16* h_buf, const float* __restrict__ coef,
                         const float* __restrict__ c0, float* __restrict__ out,
                         unsigned* __restrict__ flags) {
    __shared__ bf16x8 W2L[4 * 16 * 64];   // [e][kk][lane] fragments, 64KB
    __shared__ bf16x8 W1L[32 * 64];       // [kk][lane] fragments, 32KB

    const int wg   = blockIdx.x;      // 0..255
    const int wgh  = wg & 127;        // owns units j0..j0+3 (both waves)
    const int j0   = wgh << 2;
    const int tid  = threadIdx.x;     // 0..127
    const int lane = tid & 63;
    const int wv   = tid >> 6;        // wave 0,1
    const int qt   = ((wg >> 7) << 1) + wv;   // this WAVE's quarter 0..3

    const int rlo  = lane & 15;       // MFMA col within 16: rlo = q*4 + jj
    const int kg   = lane >> 4;       // k-group / C row-quad
    const int q    = rlo >> 2;        // gate index of this lane's col
    const int jj   = rlo & 3;         // unit-within-WG
    const int s16  = (kg << 2) + q;   // local sample of my cell
    const int samp = (qt << 4) + s16; // global sample
    const int arow = (qt << 4) + rlo; // global A1 row this lane loads
    const int o_ln = (q << 9) + j0 + jj;   // this lane's gate column

    // ---- build LDS weight fragments (verbatim R14/R16) ----
    for (int g = tid; g < 4096; g += 128) {
        int e = g >> 10, kk = (g >> 6) & 15, l = g & 63;
        int rl = l & 15, kgg = l >> 4;
        int o = ((rl >> 2) << 9) + j0 + (rl & 3);
        W2L[g] = *(const bf16x8*)(W2T + ((size_t)o << 11) + (e << 9) + (kk << 5) + (kgg << 3));
    }
    for (int g = tid; g < 2048; g += 128) {
        int kk = g >> 6, l = g & 63;
        int rl = l & 15, kgg = l >> 4;
        int o = ((rl >> 2) << 9) + j0 + (rl & 3);
        W1L[g] = *(const bf16x8*)(W1T + ((size_t)o << 10) + (kk << 5) + (kgg << 3));
    }

    // ---- per-lane constants in registers ----
    float bias_r[4];
    float4 cw[4];
#pragma unroll
    for (int r = 0; r < 4; ++r) {
        int row = (qt << 4) + (kg << 2) + r;   // global sample row of C quad
        bias_r[r] = biasmix[((size_t)row << 11) + o_ln];
        cw[r] = *(const float4*)(coef + (row << 2));
    }
    float c_reg = c0[((size_t)samp << 9) + j0 + jj];

    // per-quarter h buffer (8 slots x 8192 elems = 16KB/slot) and flag block
    bf16* hB = h_buf + (size_t)qt * (ZSLOTS * 8192);
    unsigned* flagB = flags + (qt << 7);

    __syncthreads();   // LDS weights ready (only barrier in the kernel)

    f32x4 acc0, acc1, acc2, acc3;   // input-part accumulators (overlap slot)
    {
        const bf16x8* xa = (const bf16x8*)A1 + ((size_t)arow << 7) + kg;
        acc0 = (f32x4){0.f, 0.f, 0.f, 0.f}; acc1 = acc0; acc2 = acc0; acc3 = acc0;
#pragma unroll
        for (int kk = 0; kk < 32; ++kk) {
            bf16x8 a = xa[kk << 2];
            bf16x8 b = W1L[(kk << 6) + lane];
            f32x4& ac = (kk & 3) == 0 ? acc0 : (kk & 3) == 1 ? acc1 : (kk & 3) == 2 ? acc2 : acc3;
            ac = __builtin_amdgcn_mfma_f32_16x16x32_bf16(a, b, ac, 0, 0, 0);
        }
    }

    float spin = 1.0f;   // FMA-backoff accumulator (kept live via asm sink)

    for (int t = 0; t < T_STEPS; ++t) {
        // ---- wait for epoch t: ONE u64 flag load per lane (128 flags/qt) ----
        if (t) {
            const unsigned long long* f64 = (const unsigned long long*)flagB + lane;
            const unsigned tt = (unsigned)t;
            while (true) {
                unsigned long long v = __hip_atomic_load(f64, __ATOMIC_RELAXED,
                                                         __HIP_MEMORY_SCOPE_AGENT);
                if ((unsigned)v >= tt && (unsigned)(v >> 32) >= tt) break;
#pragma unroll
                for (int i = 0; i < 24; ++i)           // ~100cy dependent chain
                    spin = __builtin_fmaf(spin, 1.0000001f, 1e-30f);
                asm volatile("" :: "v"(spin));          // keep live (no DCE)
            }
        }

        // h slots transposed: hq[ug=wgh][s16], 8B entries, 16KB/slot
        const bf16* hin  = hB + (((size_t)t & (ZSLOTS - 1)) << 13);
        bf16*       hout = hB + (((size_t)(t + 1) & (ZSLOTS - 1)) << 13);

        // ---- hidden GEMM: 32 LLC-direct 8B atomic loads, 4-expert MFMA ----
        f32x4 e0 = {0.f, 0.f, 0.f, 0.f}, e1 = e0, e2 = e0, e3 = e0;
        {
            const unsigned long long* hq = (const unsigned long long*)hin;
            bf16x8 areg[16];
#pragma unroll
            for (int kk = 0; kk < 16; ++kk) {
                int ug = (kk << 3) + (kg << 1);
                unsigned long long lo = __hip_atomic_load(hq + (ug << 4) + rlo,
                                                          __ATOMIC_RELAXED, __HIP_MEMORY_SCOPE_AGENT);
                unsigned long long hi = __hip_atomic_load(hq + ((ug + 1) << 4) + rlo,
                                                          __ATOMIC_RELAXED, __HIP_MEMORY_SCOPE_AGENT);
                u64x2 t2; t2[0] = lo; t2[1] = hi;
                areg[kk] = __builtin_bit_cast(bf16x8, t2);
            }
#pragma unroll
            for (int kk = 0; kk < 16; ++kk) {
                e0 = __builtin_amdgcn_mfma_f32_16x16x32_bf16(areg[kk], W2L[(kk << 6) + lane       ], e0, 0, 0, 0);
                e1 = __builtin_amdgcn_mfma_f32_16x16x32_bf16(areg[kk], W2L[(kk << 6) + lane + 1024], e1, 0, 0, 0);
                e2 = __builtin_amdgcn_mfma_f32_16x16x32_bf16(areg[kk], W2L[(kk << 6) + lane + 2048], e2, 0, 0, 0);
                e3 = __builtin_amdgcn_mfma_f32_16x16x32_bf16(areg[kk], W2L[(kk << 6) + lane + 3072], e3, 0, 0, 0);
            }
        }

        // ---- epilogue in registers: g = sum_e coef*acc_e + xg + bias ----
        f32x4 gv;
        {
            f32x4 xin = (acc0 + acc1) + (acc2 + acc3);
#pragma unroll
            for (int r = 0; r < 4; ++r)
                gv[r] = e0[r] * cw[r].x + e1[r] * cw[r].y + e2[r] * cw[r].z + e3[r] * cw[r].w
                      + xin[r] + bias_r[r];
        }

        // ---- gate exchange among 4 gate-lanes (xor 4/8/12) — verified R10 ----
        const bool b0 = (q & 1), b1 = (q & 2);
        float own = b1 ? (b0 ? gv[3] : gv[2]) : (b0 ? gv[1] : gv[0]);   // g[q]
        float s1  = b1 ? (b0 ? gv[2] : gv[3]) : (b0 ? gv[0] : gv[1]);   // g[q^1]
        float s2  = b1 ? (b0 ? gv[1] : gv[0]) : (b0 ? gv[3] : gv[2]);   // g[q^2]
        float s3  = b1 ? (b0 ? gv[0] : gv[1]) : (b0 ? gv[2] : gv[3]);   // g[q^3]
        float r1 = __shfl_xor(s1, 4);
        float r2 = __shfl_xor(s2, 8);
        float r3 = __shfl_xor(s3, 12);
        float iG = (q == 0) ? own : (q == 1) ? r1 : (q == 2) ? r2 : r3;
        float fG = (q == 0) ? r1 : (q == 1) ? own : (q == 2) ? r3 : r2;
        float cG = (q == 0) ? r2 : (q == 1) ? r3 : (q == 2) ? own : r1;
        float oG = (q == 0) ? r3 : (q == 1) ? r2 : (q == 2) ? r1 : own;

        // ---- cell update (1 cell per lane) ----
        float ig = 1.f / (1.f + __expf(-iG));
        float fg = 1.f / (1.f + __expf(-fG));
        float cc = tanhf(cG);
        float og = 1.f / (1.f + __expf(-oG));
        float cn = fg * c_reg + ig * cc;
        float hv = og * tanhf(cn);
        c_reg = cn;

        // ---- pack 4 units of my sample via butterfly over jj (verified R10) ----
        unsigned u = (unsigned)f2bf(hv);
        unsigned w = (unsigned)__shfl_xor((int)u, 1);
        unsigned pair = (jj & 1) ? (w | (u << 16)) : (u | (w << 16));
        unsigned p2 = (unsigned)__shfl_xor((int)pair, 2);
        unsigned long long v64 = (jj & 2)
            ? ((unsigned long long)p2 | ((unsigned long long)pair << 32))
            : ((unsigned long long)pair | ((unsigned long long)p2 << 32));
        // TRANSPOSED store: wave's 16 stores = ONE contiguous 128B line
        if (jj == 0)
            __hip_atomic_store((unsigned long long*)hout + (wgh << 4) + s16,
                               v64, __ATOMIC_RELAXED, __HIP_MEMORY_SCOPE_AGENT);

        // ---- release: drain (1 line) + single per-wave flag ----
        asm volatile("s_waitcnt vmcnt(0)" ::: "memory");
        if (lane == 0)
            __hip_atomic_store(&flagB[wgh], (unsigned)(t + 1),
                               __ATOMIC_RELAXED, __HIP_MEMORY_SCOPE_AGENT);

        // ---- post-arrive (off critical path): next input GEMM first (gets
        //      its L2/LLC loads flying), then HBM out stores ----
        if (t + 1 < T_STEPS) {
            const bf16x8* xa = (const bf16x8*)A1 + ((size_t)(((t + 1) << 6) + arow) << 7) + kg;
            acc0 = (f32x4){0.f, 0.f, 0.f, 0.f}; acc1 = acc0; acc2 = acc0; acc3 = acc0;
#pragma unroll
            for (int kk = 0; kk < 32; ++kk) {
                bf16x8 a = xa[kk << 2];
                bf16x8 b = W1L[(kk << 6) + lane];
                f32x4& ac = (kk & 3) == 0 ? acc0 : (kk & 3) == 1 ? acc1 : (kk & 3) == 2 ? acc2 : acc3;
                ac = __builtin_amdgcn_mfma_f32_16x16x32_bf16(a, b, ac, 0, 0, 0);
            }
        }
        out[((size_t)t << 15) + ((size_t)samp << 9) + j0 + jj] = hv;
        if (t == T_STEPS - 1) {
            size_t base = (size_t)T_STEPS << 15;
            out[base + ((size_t)samp << 9) + j0 + jj] = hv;
            out[base + (1 << 15) + ((size_t)samp << 9) + j0 + jj] = cn;
        }
    }
}

// ---------------- launch (geometry verbatim R14/R16) ----------------
extern "C" void kernel_launch(void* const* d_in, const int* in_sizes, int n_in,
                              void* d_out, int out_size, void* d_ws, size_t ws_size,
                              hipStream_t stream) {
    const float* x    = (const float*)d_in[0];
    const float* h0   = (const float*)d_in[1];
    const float* c0   = (const float*)d_in[2];
    const float* coef = (const float*)d_in[3];
    const float* Wi   = (const float*)d_in[4];
    const float* bi   = (const float*)d_in[5];
    const float* Wh   = (const float*)d_in[6];
    const float* bh   = (const float*)d_in[7];
    float* out = (float*)d_out;

    char* ws = (char*)d_ws;
    bf16*   W2T     = (bf16*)(ws);                                   // 8 MB
    bf16*   W1T     = (bf16*)(ws + (8u  << 20));                     // 4 MB
    bf16*   A1      = (bf16*)(ws + (12u << 20));                     // 16 MB
    float*  biasmix = (float*)(ws + (28u << 20));                    // 512 KB
    bf16*   h_buf   = (bf16*)(ws + (28u << 20) + (512u << 10));      // 512 KB (4x8x16KB)
    unsigned* flags = (unsigned*)(ws + (29u << 20));                 // 2 KB

    prep_w2t <<<16384, 256, 0, stream>>>(Wh, W2T);
    prep_w1t <<< 8192, 256, 0, stream>>>(Wi, W1T);
    prep_a1  <<<32768, 256, 0, stream>>>(x, coef, A1);
    prep_bias<<<  512, 256, 0, stream>>>(coef, bi, bh, biasmix);
    prep_h0  <<<  128, 256, 0, stream>>>(h0, h_buf, flags);

    void* args[] = {(void*)&W2T, (void*)&W1T, (void*)&A1, (void*)&biasmix,
                    (void*)&h_buf, (void*)&coef, (void*)&c0, (void*)&out, (void*)&flags};
    hipLaunchCooperativeKernel((void*)lstm_rec, dim3(NWG), dim3(128), args, 0, stream);
}